// Round 7
// baseline (194.382 us; speedup 1.0000x reference)
//
#include <hip/hip_runtime.h>

// CGCConv: out = (scatter_add(ew*pr[src]*x[src], dst) + x) @ W.T + b
// N=50000, E=800000, D=96, fp32.
//
// Round 7:
//  - k_sortpull: fuse sortB+pull. One block per 128-node bucket: LDS counting
//    sort (entries stay in LDS) then pull-aggregate straight from LDS —
//    kills the 12.8MB sorted-stage writeback/re-read, offs/counts, 1 launch.
//  - k_prep: binA + bf16-cvt merged (independent; binA blocks first).
//  - Buckets 128 nodes (NB=391, CAPB=2432=mu+8.5sig), EPB=4096 (runs ~168B
//    > 128B line -> less cross-XCD boundary fragmentation in binA stores).
// Pipeline (4 launches): zero -> prep -> sortpull -> gemm.

constexpr int NN = 50000;
constexpr int NE = 800000;
constexpr int DD = 96;
constexpr int NB = 391;                       // buckets: dst>>7 (128 nodes)
constexpr int CAPB = 2432;                    // mu=2048 + 8.5 sigma
constexpr int EPB = 4096;                     // edges per binA block
constexpr int NBLK = (NE + EPB - 1) / EPB;    // 196
constexpr int NCVT = (NN * DD / 4 + 511) / 512;  // 2344 cvt blocks

__device__ inline unsigned short f2bf(float f) {    // RNE fp32->bf16
    unsigned u = __float_as_uint(f);
    return (unsigned short)((u + 0x7FFFu + ((u >> 16) & 1u)) >> 16);
}
__device__ inline float bfh(unsigned short v) {
    return __uint_as_float((unsigned)v << 16);
}

__global__ __launch_bounds__(512) void k_zero(int* __restrict__ cur1) {
    if (threadIdx.x < NB) cur1[threadIdx.x] = 0;
}

// Blocks [0,NBLK): bucket-bin edges (entry = {src | dloc<<16, coef}; one
// global atomic per (block,bucket) -> contiguous single-CU runs ~168B).
// Blocks [NBLK,NBLK+NCVT): y16 = bf16(x).
__global__ __launch_bounds__(512) void k_prep(const int* __restrict__ src,
                                              const int* __restrict__ dst,
                                              const float* __restrict__ ew,
                                              const float* __restrict__ pr,
                                              int* __restrict__ cur1,
                                              int2* __restrict__ stage,
                                              const float4* __restrict__ x4,
                                              ushort4* __restrict__ y16v) {
    int tid = threadIdx.x;
    if (blockIdx.x >= NBLK) {                 // cvt phase
        int i = (blockIdx.x - NBLK) * 512 + tid;
        if (i < NN * DD / 4) {
            float4 v = x4[i];
            y16v[i] = make_ushort4(f2bf(v.x), f2bf(v.y), f2bf(v.z), f2bf(v.w));
        }
        return;
    }
    __shared__ int h[NB];
    __shared__ int gb[NB];
    for (int i = tid; i < NB; i += 512) h[i] = 0;
    __syncthreads();
    int base = blockIdx.x * EPB;

    int2 ent[8]; int bkt[8]; int lrk[8];
    #pragma unroll
    for (int j = 0; j < 8; j++) {
        int e = base + j * 512 + tid;
        bkt[j] = -1;
        if (e < NE) {
            int d = dst[e];
            int s = src[e];
            float c = ew[e] * pr[s];
            bkt[j] = d >> 7;
            lrk[j] = atomicAdd(&h[d >> 7], 1);
            ent[j] = make_int2(s | ((d & 127) << 16), __float_as_int(c));
        }
    }
    __syncthreads();
    for (int i = tid; i < NB; i += 512)
        gb[i] = h[i] ? atomicAdd(&cur1[i], h[i]) : 0;
    __syncthreads();
    #pragma unroll
    for (int j = 0; j < 8; j++)
        if (bkt[j] >= 0)
            stage[(size_t)bkt[j] * CAPB + gb[bkt[j]] + lrk[j]] = ent[j];
}

// One block per bucket: LDS counting-sort by dloc, then pull-aggregate from
// LDS. 8 wave-groups; lane<48 owns 2 channels (ushort2 bf16 gather); entry
// reads are same-address LDS broadcasts. Residual +x fp32; out written once.
__global__ __launch_bounds__(512) void k_sortpull(const int2* __restrict__ stage,
                                                  const int* __restrict__ cur1,
                                                  const ushort2* __restrict__ y2,
                                                  const float2* __restrict__ x2,
                                                  float2* __restrict__ out2) {
    __shared__ int2 es[CAPB];
    __shared__ int h[128];
    __shared__ int sc[128];
    int b = blockIdx.x, tid = threadIdx.x;
    size_t base = (size_t)b * CAPB;
    int n = cur1[b];

    if (tid < 128) h[tid] = 0;
    __syncthreads();
    int2 ent[5]; int lrk[5];
    int m = 0;
    for (int i = tid; i < n; i += 512) {
        int2 e = stage[base + i];
        lrk[m] = atomicAdd(&h[(e.x >> 16) & 127], 1);
        ent[m] = e; m++;
    }
    __syncthreads();
    if (tid < 128) sc[tid] = h[tid];
    __syncthreads();
    #pragma unroll
    for (int o = 1; o < 128; o <<= 1) {
        int t = 0;
        if (tid < 128 && tid >= o) t = sc[tid - o];
        __syncthreads();
        if (tid < 128) sc[tid] += t;          // inclusive scan
        __syncthreads();
    }
    m = 0;
    for (int i = tid; i < n; i += 512) {
        int2 e = ent[m];
        int dl = (e.x >> 16) & 127;
        es[sc[dl] - h[dl] + lrk[m]] = e;      // exclusive + rank
        m++;
    }
    __syncthreads();

    int grp = tid >> 6, lane = tid & 63;      // 8 wave-groups
    for (int ni = grp; ni < 128; ni += 8) {
        int d = (b << 7) + ni;
        if (d >= NN) break;                   // wave-uniform
        int beg = sc[ni] - h[ni];
        int deg = h[ni];
        float a0 = 0.f, a1 = 0.f;
        int k = 0;
        for (; k + 4 <= deg; k += 4) {
            int2 e0 = es[beg + k],     e1 = es[beg + k + 1];
            int2 e2 = es[beg + k + 2], e3 = es[beg + k + 3];
            if (lane < 48) {
                ushort2 u0 = y2[(size_t)(e0.x & 0xffff) * 48 + lane];
                ushort2 u1 = y2[(size_t)(e1.x & 0xffff) * 48 + lane];
                ushort2 u2 = y2[(size_t)(e2.x & 0xffff) * 48 + lane];
                ushort2 u3 = y2[(size_t)(e3.x & 0xffff) * 48 + lane];
                float c0 = __int_as_float(e0.y), c1 = __int_as_float(e1.y);
                float c2 = __int_as_float(e2.y), c3 = __int_as_float(e3.y);
                a0 += c0 * bfh(u0.x) + c1 * bfh(u1.x)
                    + c2 * bfh(u2.x) + c3 * bfh(u3.x);
                a1 += c0 * bfh(u0.y) + c1 * bfh(u1.y)
                    + c2 * bfh(u2.y) + c3 * bfh(u3.y);
            }
        }
        for (; k < deg; k++) {
            int2 e = es[beg + k];
            if (lane < 48) {
                ushort2 u = y2[(size_t)(e.x & 0xffff) * 48 + lane];
                float c = __int_as_float(e.y);
                a0 += c * bfh(u.x);
                a1 += c * bfh(u.y);
            }
        }
        if (lane < 48) {
            float2 xv = x2[(size_t)d * 48 + lane];
            out2[(size_t)d * 48 + lane] = make_float2(a0 + xv.x, a1 + xv.y);
        }
    }
}

// In-place row GEMM (unchanged): io[r,o] = sum_d io[r,d]*Wt[d,o]+b[o].
constexpr int SWS = 100;
__global__ __launch_bounds__(256, 4) void k_gemm(float* __restrict__ io,
                                                 const float* __restrict__ W,
                                                 const float* __restrict__ b) {
    __shared__ float sWt[DD * SWS];   // [d][o]
    int tid = threadIdx.x;
    for (int i = tid; i < DD * DD; i += 256) {
        int o = i / DD, d = i - o * DD;
        sWt[d * SWS + o] = W[i];
    }
    __syncthreads();

    int wave = tid >> 6, lane = tid & 63;
    int og = lane & 7, rgl = lane >> 3;
    int o0 = og * 12;
    int rbase = blockIdx.x * 128 + wave * 32 + rgl;
    const float4* io4 = (const float4*)io;

    int r[4];
    #pragma unroll
    for (int t = 0; t < 4; t++) {
        int rr = rbase + 8 * t;
        r[t] = (rr < NN) ? rr : (NN - 1);
    }

    float acc[4][12];
    #pragma unroll
    for (int t = 0; t < 4; t++)
        #pragma unroll
        for (int m = 0; m < 12; m++) acc[t][m] = 0.f;

    for (int d4 = 0; d4 < 24; d4++) {
        float4 xv[4];
        #pragma unroll
        for (int t = 0; t < 4; t++) xv[t] = io4[(size_t)r[t] * 24 + d4];
        #pragma unroll
        for (int dj = 0; dj < 4; dj++) {
            const float* wp = &sWt[(d4 * 4 + dj) * SWS + o0];
            float4 w0 = *(const float4*)(wp);
            float4 w1 = *(const float4*)(wp + 4);
            float4 w2 = *(const float4*)(wp + 8);
            #pragma unroll
            for (int t = 0; t < 4; t++) {
                float xs = (dj == 0) ? xv[t].x : (dj == 1) ? xv[t].y
                         : (dj == 2) ? xv[t].z : xv[t].w;
                acc[t][0]  += xs * w0.x;  acc[t][1]  += xs * w0.y;
                acc[t][2]  += xs * w0.z;  acc[t][3]  += xs * w0.w;
                acc[t][4]  += xs * w1.x;  acc[t][5]  += xs * w1.y;
                acc[t][6]  += xs * w1.z;  acc[t][7]  += xs * w1.w;
                acc[t][8]  += xs * w2.x;  acc[t][9]  += xs * w2.y;
                acc[t][10] += xs * w2.z;  acc[t][11] += xs * w2.w;
            }
        }
    }

    float4 b0 = *(const float4*)(b + o0);
    float4 b1 = *(const float4*)(b + o0 + 4);
    float4 b2 = *(const float4*)(b + o0 + 8);
    float4* io4w = (float4*)io;
    #pragma unroll
    for (int t = 0; t < 4; t++) {
        int rr = rbase + 8 * t;
        if (rr < NN) {
            size_t base = (size_t)rr * 24 + og * 3;
            io4w[base + 0] = make_float4(acc[t][0] + b0.x, acc[t][1] + b0.y,
                                         acc[t][2] + b0.z, acc[t][3] + b0.w);
            io4w[base + 1] = make_float4(acc[t][4] + b1.x, acc[t][5] + b1.y,
                                         acc[t][6] + b1.z, acc[t][7] + b1.w);
            io4w[base + 2] = make_float4(acc[t][8] + b2.x, acc[t][9] + b2.y,
                                         acc[t][10] + b2.z, acc[t][11] + b2.w);
        }
    }
}

extern "C" void kernel_launch(void* const* d_in, const int* in_sizes, int n_in,
                              void* d_out, int out_size, void* d_ws, size_t ws_size,
                              hipStream_t stream) {
    const float* x  = (const float*)d_in[0];
    const int*   ei = (const int*)d_in[1];   // [2,E]: [0..E)=src, [E..2E)=dst
    const float* ew = (const float*)d_in[2];
    const float* pr = (const float*)d_in[3];
    const float* W  = (const float*)d_in[4];
    const float* b  = (const float*)d_in[5];
    float* out = (float*)d_out;

    // ws layout (~17.2 MB)
    int2* stage = (int2*)d_ws;                        // NB*CAPB int2 (7.6MB)
    unsigned short* y16 = (unsigned short*)(stage + (size_t)NB * CAPB);  // 9.6MB
    int* cur1 = (int*)(y16 + (size_t)NN * DD);        // 391 ints

    const int* src = ei;
    const int* dst = ei + NE;

    k_zero<<<1, 512, 0, stream>>>(cur1);
    k_prep<<<NBLK + NCVT, 512, 0, stream>>>(src, dst, ew, pr, cur1, stage,
                                            (const float4*)x, (ushort4*)y16);
    k_sortpull<<<NB, 512, 0, stream>>>(stage, cur1, (const ushort2*)y16,
                                       (const float2*)x, (float2*)out);
    k_gemm<<<(NN + 127) / 128, 256, 0, stream>>>(out, W, b);
}

// Round 8
// 179.557 us; speedup vs baseline: 1.0826x; 1.0826x over previous
//
#include <hip/hip_runtime.h>

// CGCConv: out = (scatter_add(ew*pr[src]*x[src], dst) + x) @ W.T + b
// N=50000, E=800000, D=96, fp32.
//
// Round 8 = Round 6 structure (best: 166.6us) + occupancy-neutral tweaks.
// R7's fused sortpull REGRESSED (80us): 391 blocks x 40KB LDS -> 25% occupancy
// starved the latency-bound gather. Lesson: keep pull at high occupancy.
//  - k_prep: binA + bf16-cvt in one launch (independent; overlap). EPB=4096
//    -> per-(block,bucket) runs ~168B > line (less cross-XCD fragmentation).
//  - Non-temporal u64 loads/stores for stage (write-once/read-once stream)
//    to keep y16 resident in L2.
//  - k_pull: edge loop unrolled x8 (8 outstanding entry loads + 8 gathers).
// Pipeline (5 launches): zero -> prep -> sortB -> pull -> gemm.

constexpr int NN = 50000;
constexpr int NE = 800000;
constexpr int DD = 96;
constexpr int NB = 196;                       // buckets: dst>>8 (256 nodes)
constexpr int CAPB = 4608;                    // mu=4082 + 8 sigma
constexpr int EPB = 4096;                     // edges per binA block
constexpr int NBLK = (NE + EPB - 1) / EPB;    // 196
constexpr int NCVT = (NN * DD / 4 + 511) / 512;  // 2344 cvt blocks

__device__ inline unsigned short f2bf(float f) {    // RNE fp32->bf16
    unsigned u = __float_as_uint(f);
    return (unsigned short)((u + 0x7FFFu + ((u >> 16) & 1u)) >> 16);
}
__device__ inline float bfh(unsigned short v) {
    return __uint_as_float((unsigned)v << 16);
}
__device__ inline unsigned long long pack_e(int meta, float c) {
    return (unsigned long long)(unsigned)meta |
           ((unsigned long long)(unsigned)__float_as_uint(c) << 32);
}

__global__ __launch_bounds__(256) void k_zero(int* __restrict__ cur1) {
    if (threadIdx.x < NB) cur1[threadIdx.x] = 0;
}

// Blocks [0,NBLK): bucket-bin edges, entry = {src | dloc<<16, coef} as u64.
// One global atomic per (block,bucket) reserves a contiguous single-CU run.
// Blocks [NBLK,NBLK+NCVT): y16 = bf16(x).
__global__ __launch_bounds__(512) void k_prep(const int* __restrict__ src,
                                              const int* __restrict__ dst,
                                              const float* __restrict__ ew,
                                              const float* __restrict__ pr,
                                              int* __restrict__ cur1,
                                              unsigned long long* __restrict__ stage,
                                              const float4* __restrict__ x4,
                                              ushort4* __restrict__ y16v) {
    int tid = threadIdx.x;
    if (blockIdx.x >= NBLK) {                 // cvt phase
        int i = (blockIdx.x - NBLK) * 512 + tid;
        if (i < NN * DD / 4) {
            float4 v = x4[i];
            y16v[i] = make_ushort4(f2bf(v.x), f2bf(v.y), f2bf(v.z), f2bf(v.w));
        }
        return;
    }
    __shared__ int h[NB];
    __shared__ int gb[NB];
    for (int i = tid; i < NB; i += 512) h[i] = 0;
    __syncthreads();
    int base = blockIdx.x * EPB;

    unsigned long long ent[8]; int bkt[8]; int lrk[8];
    #pragma unroll
    for (int j = 0; j < 8; j++) {
        int e = base + j * 512 + tid;
        bkt[j] = -1;
        if (e < NE) {
            int d = dst[e];
            int s = src[e];
            float c = ew[e] * pr[s];
            bkt[j] = d >> 8;
            lrk[j] = atomicAdd(&h[d >> 8], 1);
            ent[j] = pack_e(s | ((d & 255) << 16), c);
        }
    }
    __syncthreads();
    for (int i = tid; i < NB; i += 512)
        gb[i] = h[i] ? atomicAdd(&cur1[i], h[i]) : 0;
    __syncthreads();
    #pragma unroll
    for (int j = 0; j < 8; j++)
        if (bkt[j] >= 0)
            __builtin_nontemporal_store(
                ent[j], &stage[(size_t)bkt[j] * CAPB + gb[bkt[j]] + lrk[j]]);
}

// Per-bucket in-place counting sort by dloc; emits offs/counts (offs absolute
// into padded stage). Block-private region => in-place safe. nt stream I/O.
__global__ __launch_bounds__(512) void k_sortB(unsigned long long* __restrict__ stage,
                                               const int* __restrict__ cur1,
                                               int* __restrict__ offs,
                                               int* __restrict__ counts) {
    __shared__ int h[256];
    __shared__ int sc[256];
    __shared__ unsigned long long sorted[CAPB];
    int b = blockIdx.x;
    int tid = threadIdx.x;
    size_t base = (size_t)b * CAPB;
    int n = cur1[b];

    for (int i = tid; i < 256; i += 512) h[i] = 0;
    __syncthreads();

    unsigned long long ent[9]; int lrk[9];
    int m = 0;
    for (int i = tid; i < n; i += 512) {
        unsigned long long e = __builtin_nontemporal_load(&stage[base + i]);
        int dloc = ((int)e >> 16) & 0xff;
        lrk[m] = atomicAdd(&h[dloc], 1);
        ent[m] = e;
        m++;
    }
    __syncthreads();
    if (tid < 256) sc[tid] = h[tid];
    __syncthreads();
    #pragma unroll
    for (int o = 1; o < 256; o <<= 1) {
        int t = 0;
        if (tid < 256 && tid >= o) t = sc[tid - o];
        __syncthreads();
        if (tid < 256) sc[tid] += t;     // inclusive
        __syncthreads();
    }
    m = 0;
    for (int i = tid; i < n; i += 512) {
        unsigned long long e = ent[m];
        int dloc = ((int)e >> 16) & 0xff;
        sorted[sc[dloc] - h[dloc] + lrk[m]] = e;   // exclusive + rank
        m++;
    }
    __syncthreads();
    for (int i = tid; i < n; i += 512)
        __builtin_nontemporal_store(sorted[i], &stage[base + i]);
    if (tid < 256) {
        int d = (b << 8) + tid;
        if (d < NN) {
            offs[d] = (int)base + sc[tid] - h[tid];
            counts[d] = h[tid];
        }
    }
}

// Pull-aggregate: 8 nodes/block, 32 lanes/node, lanes 0..23 own one ushort4
// (4 bf16 channels, 8B gather). Edge loop unrolled x8 for MLP; nt entry loads.
__global__ __launch_bounds__(256) void k_pull(const ushort4* __restrict__ y16v,
                                              const float4* __restrict__ x4,
                                              const int* __restrict__ offs,
                                              const int* __restrict__ counts,
                                              const unsigned long long* __restrict__ ep,
                                              float4* __restrict__ out4) {
    int g = blockIdx.x * 8 + (threadIdx.x >> 5);
    int lane = threadIdx.x & 31;
    if (g >= NN || lane >= 24) return;
    int beg = offs[g];
    int deg = counts[g];
    float ax = 0.f, ay = 0.f, az = 0.f, aw = 0.f;
    int k = 0;
    for (; k + 8 <= deg; k += 8) {
        unsigned long long e[8];
        #pragma unroll
        for (int j = 0; j < 8; j++)
            e[j] = __builtin_nontemporal_load(&ep[beg + k + j]);
        ushort4 u[8];
        #pragma unroll
        for (int j = 0; j < 8; j++)
            u[j] = y16v[(size_t)((unsigned)e[j] & 0xffff) * 24 + lane];
        #pragma unroll
        for (int j = 0; j < 8; j++) {
            float c = __uint_as_float((unsigned)(e[j] >> 32));
            ax += c * bfh(u[j].x);
            ay += c * bfh(u[j].y);
            az += c * bfh(u[j].z);
            aw += c * bfh(u[j].w);
        }
    }
    for (; k + 4 <= deg; k += 4) {
        unsigned long long e[4];
        #pragma unroll
        for (int j = 0; j < 4; j++)
            e[j] = __builtin_nontemporal_load(&ep[beg + k + j]);
        ushort4 u[4];
        #pragma unroll
        for (int j = 0; j < 4; j++)
            u[j] = y16v[(size_t)((unsigned)e[j] & 0xffff) * 24 + lane];
        #pragma unroll
        for (int j = 0; j < 4; j++) {
            float c = __uint_as_float((unsigned)(e[j] >> 32));
            ax += c * bfh(u[j].x);
            ay += c * bfh(u[j].y);
            az += c * bfh(u[j].z);
            aw += c * bfh(u[j].w);
        }
    }
    for (; k < deg; k++) {
        unsigned long long e = __builtin_nontemporal_load(&ep[beg + k]);
        ushort4 u = y16v[(size_t)((unsigned)e & 0xffff) * 24 + lane];
        float c = __uint_as_float((unsigned)(e >> 32));
        ax += c * bfh(u.x);
        ay += c * bfh(u.y);
        az += c * bfh(u.z);
        aw += c * bfh(u.w);
    }
    float4 xn = x4[(size_t)g * 24 + lane];
    out4[(size_t)g * 24 + lane] = make_float4(ax + xn.x, ay + xn.y,
                                              az + xn.z, aw + xn.w);
}

// In-place row GEMM (unchanged, 13us proven): io[r,o]=sum_d io[r,d]*Wt[d,o]+b[o].
constexpr int SWS = 100;
__global__ __launch_bounds__(256, 4) void k_gemm(float* __restrict__ io,
                                                 const float* __restrict__ W,
                                                 const float* __restrict__ b) {
    __shared__ float sWt[DD * SWS];   // [d][o]
    int tid = threadIdx.x;
    for (int i = tid; i < DD * DD; i += 256) {
        int o = i / DD, d = i - o * DD;
        sWt[d * SWS + o] = W[i];
    }
    __syncthreads();

    int wave = tid >> 6, lane = tid & 63;
    int og = lane & 7, rgl = lane >> 3;
    int o0 = og * 12;
    int rbase = blockIdx.x * 128 + wave * 32 + rgl;
    const float4* io4 = (const float4*)io;

    int r[4];
    #pragma unroll
    for (int t = 0; t < 4; t++) {
        int rr = rbase + 8 * t;
        r[t] = (rr < NN) ? rr : (NN - 1);
    }

    float acc[4][12];
    #pragma unroll
    for (int t = 0; t < 4; t++)
        #pragma unroll
        for (int m = 0; m < 12; m++) acc[t][m] = 0.f;

    for (int d4 = 0; d4 < 24; d4++) {
        float4 xv[4];
        #pragma unroll
        for (int t = 0; t < 4; t++) xv[t] = io4[(size_t)r[t] * 24 + d4];
        #pragma unroll
        for (int dj = 0; dj < 4; dj++) {
            const float* wp = &sWt[(d4 * 4 + dj) * SWS + o0];
            float4 w0 = *(const float4*)(wp);
            float4 w1 = *(const float4*)(wp + 4);
            float4 w2 = *(const float4*)(wp + 8);
            #pragma unroll
            for (int t = 0; t < 4; t++) {
                float xs = (dj == 0) ? xv[t].x : (dj == 1) ? xv[t].y
                         : (dj == 2) ? xv[t].z : xv[t].w;
                acc[t][0]  += xs * w0.x;  acc[t][1]  += xs * w0.y;
                acc[t][2]  += xs * w0.z;  acc[t][3]  += xs * w0.w;
                acc[t][4]  += xs * w1.x;  acc[t][5]  += xs * w1.y;
                acc[t][6]  += xs * w1.z;  acc[t][7]  += xs * w1.w;
                acc[t][8]  += xs * w2.x;  acc[t][9]  += xs * w2.y;
                acc[t][10] += xs * w2.z;  acc[t][11] += xs * w2.w;
            }
        }
    }

    float4 b0 = *(const float4*)(b + o0);
    float4 b1 = *(const float4*)(b + o0 + 4);
    float4 b2 = *(const float4*)(b + o0 + 8);
    float4* io4w = (float4*)io;
    #pragma unroll
    for (int t = 0; t < 4; t++) {
        int rr = rbase + 8 * t;
        if (rr < NN) {
            size_t base = (size_t)rr * 24 + og * 3;
            io4w[base + 0] = make_float4(acc[t][0] + b0.x, acc[t][1] + b0.y,
                                         acc[t][2] + b0.z, acc[t][3] + b0.w);
            io4w[base + 1] = make_float4(acc[t][4] + b1.x, acc[t][5] + b1.y,
                                         acc[t][6] + b1.z, acc[t][7] + b1.w);
            io4w[base + 2] = make_float4(acc[t][8] + b2.x, acc[t][9] + b2.y,
                                         acc[t][10] + b2.z, acc[t][11] + b2.w);
        }
    }
}

extern "C" void kernel_launch(void* const* d_in, const int* in_sizes, int n_in,
                              void* d_out, int out_size, void* d_ws, size_t ws_size,
                              hipStream_t stream) {
    const float* x  = (const float*)d_in[0];
    const int*   ei = (const int*)d_in[1];   // [2,E]: [0..E)=src, [E..2E)=dst
    const float* ew = (const float*)d_in[2];
    const float* pr = (const float*)d_in[3];
    const float* W  = (const float*)d_in[4];
    const float* b  = (const float*)d_in[5];
    float* out = (float*)d_out;

    // ws layout (~17.3 MB)
    unsigned long long* stage = (unsigned long long*)d_ws;       // NB*CAPB u64
    unsigned short* y16 = (unsigned short*)(stage + (size_t)NB * CAPB);  // 9.6MB
    int* cur1   = (int*)(y16 + (size_t)NN * DD);      // 196
    int* offs   = cur1 + NB;                          // 50000
    int* counts = offs + NN;                          // 50000

    const int* src = ei;
    const int* dst = ei + NE;

    k_zero<<<1, 256, 0, stream>>>(cur1);
    k_prep<<<NBLK + NCVT, 512, 0, stream>>>(src, dst, ew, pr, cur1, stage,
                                            (const float4*)x, (ushort4*)y16);
    k_sortB<<<NB, 512, 0, stream>>>(stage, cur1, offs, counts);
    k_pull<<<(NN + 7) / 8, 256, 0, stream>>>((const ushort4*)y16, (const float4*)x,
                                             offs, counts, stage, (float4*)out);
    k_gemm<<<(NN + 127) / 128, 256, 0, stream>>>(out, W, b);
}

// Round 9
// 154.780 us; speedup vs baseline: 1.2559x; 1.1601x over previous
//
#include <hip/hip_runtime.h>

// CGCConv: out = (scatter_add(ew*pr[src]*x[src], dst) + x) @ W.T + b
// N=50000, E=800000, D=96, fp32.
//
// Round 9 = Round 8 minus ALL non-temporal hints (the R8 regression).
// Post-mortem: stage is written-then-re-read twice (prep->sortB->pull); NT
// stores evicted it from L2, pushing 12.8MB of stream traffic to HBM.
// Keep: prep merge (binA+cvt one launch), EPB=4096, pull x8 unroll.
// Pipeline (5 launches): zero -> prep -> sortB -> pull -> gemm.

constexpr int NN = 50000;
constexpr int NE = 800000;
constexpr int DD = 96;
constexpr int NB = 196;                       // buckets: dst>>8 (256 nodes)
constexpr int CAPB = 4608;                    // mu=4082 + 8 sigma
constexpr int EPB = 4096;                     // edges per binA block
constexpr int NBLK = (NE + EPB - 1) / EPB;    // 196
constexpr int NCVT = (NN * DD / 4 + 511) / 512;  // 2344 cvt blocks

__device__ inline unsigned short f2bf(float f) {    // RNE fp32->bf16
    unsigned u = __float_as_uint(f);
    return (unsigned short)((u + 0x7FFFu + ((u >> 16) & 1u)) >> 16);
}
__device__ inline float bfh(unsigned short v) {
    return __uint_as_float((unsigned)v << 16);
}
__device__ inline unsigned long long pack_e(int meta, float c) {
    return (unsigned long long)(unsigned)meta |
           ((unsigned long long)(unsigned)__float_as_uint(c) << 32);
}

__global__ __launch_bounds__(256) void k_zero(int* __restrict__ cur1) {
    if (threadIdx.x < NB) cur1[threadIdx.x] = 0;
}

// Blocks [0,NBLK): bucket-bin edges, entry = {src | dloc<<16, coef} as u64.
// One global atomic per (block,bucket) reserves a contiguous single-CU run
// (~21 entries = 168B > line => little cross-XCD fragmentation).
// Blocks [NBLK,NBLK+NCVT): y16 = bf16(x).
__global__ __launch_bounds__(512) void k_prep(const int* __restrict__ src,
                                              const int* __restrict__ dst,
                                              const float* __restrict__ ew,
                                              const float* __restrict__ pr,
                                              int* __restrict__ cur1,
                                              unsigned long long* __restrict__ stage,
                                              const float4* __restrict__ x4,
                                              ushort4* __restrict__ y16v) {
    int tid = threadIdx.x;
    if (blockIdx.x >= NBLK) {                 // cvt phase
        int i = (blockIdx.x - NBLK) * 512 + tid;
        if (i < NN * DD / 4) {
            float4 v = x4[i];
            y16v[i] = make_ushort4(f2bf(v.x), f2bf(v.y), f2bf(v.z), f2bf(v.w));
        }
        return;
    }
    __shared__ int h[NB];
    __shared__ int gb[NB];
    for (int i = tid; i < NB; i += 512) h[i] = 0;
    __syncthreads();
    int base = blockIdx.x * EPB;

    unsigned long long ent[8]; int bkt[8]; int lrk[8];
    #pragma unroll
    for (int j = 0; j < 8; j++) {
        int e = base + j * 512 + tid;
        bkt[j] = -1;
        if (e < NE) {
            int d = dst[e];
            int s = src[e];
            float c = ew[e] * pr[s];
            bkt[j] = d >> 8;
            lrk[j] = atomicAdd(&h[d >> 8], 1);
            ent[j] = pack_e(s | ((d & 255) << 16), c);
        }
    }
    __syncthreads();
    for (int i = tid; i < NB; i += 512)
        gb[i] = h[i] ? atomicAdd(&cur1[i], h[i]) : 0;
    __syncthreads();
    #pragma unroll
    for (int j = 0; j < 8; j++)
        if (bkt[j] >= 0)
            stage[(size_t)bkt[j] * CAPB + gb[bkt[j]] + lrk[j]] = ent[j];
}

// Per-bucket in-place counting sort by dloc; emits offs/counts (offs absolute
// into padded stage). Block-private region => in-place safe.
__global__ __launch_bounds__(512) void k_sortB(unsigned long long* __restrict__ stage,
                                               const int* __restrict__ cur1,
                                               int* __restrict__ offs,
                                               int* __restrict__ counts) {
    __shared__ int h[256];
    __shared__ int sc[256];
    __shared__ unsigned long long sorted[CAPB];
    int b = blockIdx.x;
    int tid = threadIdx.x;
    size_t base = (size_t)b * CAPB;
    int n = cur1[b];

    for (int i = tid; i < 256; i += 512) h[i] = 0;
    __syncthreads();

    unsigned long long ent[9]; int lrk[9];
    int m = 0;
    for (int i = tid; i < n; i += 512) {
        unsigned long long e = stage[base + i];
        int dloc = ((int)e >> 16) & 0xff;
        lrk[m] = atomicAdd(&h[dloc], 1);
        ent[m] = e;
        m++;
    }
    __syncthreads();
    if (tid < 256) sc[tid] = h[tid];
    __syncthreads();
    #pragma unroll
    for (int o = 1; o < 256; o <<= 1) {
        int t = 0;
        if (tid < 256 && tid >= o) t = sc[tid - o];
        __syncthreads();
        if (tid < 256) sc[tid] += t;     // inclusive
        __syncthreads();
    }
    m = 0;
    for (int i = tid; i < n; i += 512) {
        unsigned long long e = ent[m];
        int dloc = ((int)e >> 16) & 0xff;
        sorted[sc[dloc] - h[dloc] + lrk[m]] = e;   // exclusive + rank
        m++;
    }
    __syncthreads();
    for (int i = tid; i < n; i += 512) stage[base + i] = sorted[i];
    if (tid < 256) {
        int d = (b << 8) + tid;
        if (d < NN) {
            offs[d] = (int)base + sc[tid] - h[tid];
            counts[d] = h[tid];
        }
    }
}

// Pull-aggregate: 8 nodes/block, 32 lanes/node, lanes 0..23 own one ushort4
// (4 bf16 channels, 8B gather). Edge loop unrolled x8 for MLP.
__global__ __launch_bounds__(256) void k_pull(const ushort4* __restrict__ y16v,
                                              const float4* __restrict__ x4,
                                              const int* __restrict__ offs,
                                              const int* __restrict__ counts,
                                              const unsigned long long* __restrict__ ep,
                                              float4* __restrict__ out4) {
    int g = blockIdx.x * 8 + (threadIdx.x >> 5);
    int lane = threadIdx.x & 31;
    if (g >= NN || lane >= 24) return;
    int beg = offs[g];
    int deg = counts[g];
    float ax = 0.f, ay = 0.f, az = 0.f, aw = 0.f;
    int k = 0;
    for (; k + 8 <= deg; k += 8) {
        unsigned long long e[8];
        #pragma unroll
        for (int j = 0; j < 8; j++) e[j] = ep[beg + k + j];
        ushort4 u[8];
        #pragma unroll
        for (int j = 0; j < 8; j++)
            u[j] = y16v[(size_t)((unsigned)e[j] & 0xffff) * 24 + lane];
        #pragma unroll
        for (int j = 0; j < 8; j++) {
            float c = __uint_as_float((unsigned)(e[j] >> 32));
            ax += c * bfh(u[j].x);
            ay += c * bfh(u[j].y);
            az += c * bfh(u[j].z);
            aw += c * bfh(u[j].w);
        }
    }
    for (; k + 4 <= deg; k += 4) {
        unsigned long long e[4];
        #pragma unroll
        for (int j = 0; j < 4; j++) e[j] = ep[beg + k + j];
        ushort4 u[4];
        #pragma unroll
        for (int j = 0; j < 4; j++)
            u[j] = y16v[(size_t)((unsigned)e[j] & 0xffff) * 24 + lane];
        #pragma unroll
        for (int j = 0; j < 4; j++) {
            float c = __uint_as_float((unsigned)(e[j] >> 32));
            ax += c * bfh(u[j].x);
            ay += c * bfh(u[j].y);
            az += c * bfh(u[j].z);
            aw += c * bfh(u[j].w);
        }
    }
    for (; k < deg; k++) {
        unsigned long long e = ep[beg + k];
        ushort4 u = y16v[(size_t)((unsigned)e & 0xffff) * 24 + lane];
        float c = __uint_as_float((unsigned)(e >> 32));
        ax += c * bfh(u.x);
        ay += c * bfh(u.y);
        az += c * bfh(u.z);
        aw += c * bfh(u.w);
    }
    float4 xn = x4[(size_t)g * 24 + lane];
    out4[(size_t)g * 24 + lane] = make_float4(ax + xn.x, ay + xn.y,
                                              az + xn.z, aw + xn.w);
}

// In-place row GEMM (unchanged, ~13us proven): io[r,o]=sum_d io[r,d]*Wt[d,o]+b[o].
constexpr int SWS = 100;
__global__ __launch_bounds__(256, 4) void k_gemm(float* __restrict__ io,
                                                 const float* __restrict__ W,
                                                 const float* __restrict__ b) {
    __shared__ float sWt[DD * SWS];   // [d][o]
    int tid = threadIdx.x;
    for (int i = tid; i < DD * DD; i += 256) {
        int o = i / DD, d = i - o * DD;
        sWt[d * SWS + o] = W[i];
    }
    __syncthreads();

    int wave = tid >> 6, lane = tid & 63;
    int og = lane & 7, rgl = lane >> 3;
    int o0 = og * 12;
    int rbase = blockIdx.x * 128 + wave * 32 + rgl;
    const float4* io4 = (const float4*)io;

    int r[4];
    #pragma unroll
    for (int t = 0; t < 4; t++) {
        int rr = rbase + 8 * t;
        r[t] = (rr < NN) ? rr : (NN - 1);
    }

    float acc[4][12];
    #pragma unroll
    for (int t = 0; t < 4; t++)
        #pragma unroll
        for (int m = 0; m < 12; m++) acc[t][m] = 0.f;

    for (int d4 = 0; d4 < 24; d4++) {
        float4 xv[4];
        #pragma unroll
        for (int t = 0; t < 4; t++) xv[t] = io4[(size_t)r[t] * 24 + d4];
        #pragma unroll
        for (int dj = 0; dj < 4; dj++) {
            const float* wp = &sWt[(d4 * 4 + dj) * SWS + o0];
            float4 w0 = *(const float4*)(wp);
            float4 w1 = *(const float4*)(wp + 4);
            float4 w2 = *(const float4*)(wp + 8);
            #pragma unroll
            for (int t = 0; t < 4; t++) {
                float xs = (dj == 0) ? xv[t].x : (dj == 1) ? xv[t].y
                         : (dj == 2) ? xv[t].z : xv[t].w;
                acc[t][0]  += xs * w0.x;  acc[t][1]  += xs * w0.y;
                acc[t][2]  += xs * w0.z;  acc[t][3]  += xs * w0.w;
                acc[t][4]  += xs * w1.x;  acc[t][5]  += xs * w1.y;
                acc[t][6]  += xs * w1.z;  acc[t][7]  += xs * w1.w;
                acc[t][8]  += xs * w2.x;  acc[t][9]  += xs * w2.y;
                acc[t][10] += xs * w2.z;  acc[t][11] += xs * w2.w;
            }
        }
    }

    float4 b0 = *(const float4*)(b + o0);
    float4 b1 = *(const float4*)(b + o0 + 4);
    float4 b2 = *(const float4*)(b + o0 + 8);
    float4* io4w = (float4*)io;
    #pragma unroll
    for (int t = 0; t < 4; t++) {
        int rr = rbase + 8 * t;
        if (rr < NN) {
            size_t base = (size_t)rr * 24 + og * 3;
            io4w[base + 0] = make_float4(acc[t][0] + b0.x, acc[t][1] + b0.y,
                                         acc[t][2] + b0.z, acc[t][3] + b0.w);
            io4w[base + 1] = make_float4(acc[t][4] + b1.x, acc[t][5] + b1.y,
                                         acc[t][6] + b1.z, acc[t][7] + b1.w);
            io4w[base + 2] = make_float4(acc[t][8] + b2.x, acc[t][9] + b2.y,
                                         acc[t][10] + b2.z, acc[t][11] + b2.w);
        }
    }
}

extern "C" void kernel_launch(void* const* d_in, const int* in_sizes, int n_in,
                              void* d_out, int out_size, void* d_ws, size_t ws_size,
                              hipStream_t stream) {
    const float* x  = (const float*)d_in[0];
    const int*   ei = (const int*)d_in[1];   // [2,E]: [0..E)=src, [E..2E)=dst
    const float* ew = (const float*)d_in[2];
    const float* pr = (const float*)d_in[3];
    const float* W  = (const float*)d_in[4];
    const float* b  = (const float*)d_in[5];
    float* out = (float*)d_out;

    // ws layout (~17.3 MB)
    unsigned long long* stage = (unsigned long long*)d_ws;       // NB*CAPB u64
    unsigned short* y16 = (unsigned short*)(stage + (size_t)NB * CAPB);  // 9.6MB
    int* cur1   = (int*)(y16 + (size_t)NN * DD);      // 196
    int* offs   = cur1 + NB;                          // 50000
    int* counts = offs + NN;                          // 50000

    const int* src = ei;
    const int* dst = ei + NE;

    k_zero<<<1, 256, 0, stream>>>(cur1);
    k_prep<<<NBLK + NCVT, 512, 0, stream>>>(src, dst, ew, pr, cur1, stage,
                                            (const float4*)x, (ushort4*)y16);
    k_sortB<<<NB, 512, 0, stream>>>(stage, cur1, offs, counts);
    k_pull<<<(NN + 7) / 8, 256, 0, stream>>>((const ushort4*)y16, (const float4*)x,
                                             offs, counts, stage, (float4*)out);
    k_gemm<<<(NN + 127) / 128, 256, 0, stream>>>(out, W, b);
}

// Round 10
// 150.994 us; speedup vs baseline: 1.2873x; 1.0251x over previous
//
#include <hip/hip_runtime.h>

// CGCConv: out = (scatter_add(ew*pr[src]*x[src], dst) + x) @ W.T + b
// N=50000, E=800000, D=96, fp32.
//
// Round 10 = Round 9 (154.8us best) + three stage-traffic cuts:
//  - prep: counting-sort the block's 4096 entries by bucket in LDS, then
//    write bucket-runs contiguously (coalesced stores; R9 scattered 8B
//    stores across ~50 lines/wave). Bucket id in spare meta bits 24-31.
//  - sortB: output entries shrink to u32 {src:16 | coef_bf16:16} (dloc is
//    implicit in sorted position); written into the first half of the
//    block's own region (private => safe). Pull's ep stream halves.
//  - sortB LDS scatter buffer u32 (18.4KB vs 36.9KB).
// Pipeline (5 launches): zero -> prep -> sortB -> pull -> gemm.

constexpr int NN = 50000;
constexpr int NE = 800000;
constexpr int DD = 96;
constexpr int NB = 196;                       // buckets: dst>>8 (256 nodes)
constexpr int CAPB = 4608;                    // mu=4082 + 8 sigma
constexpr int EPB = 4096;                     // edges per binA block
constexpr int NBLK = (NE + EPB - 1) / EPB;    // 196
constexpr int NCVT = (NN * DD / 4 + 511) / 512;  // 2344 cvt blocks

__device__ inline unsigned short f2bf(float f) {    // RNE fp32->bf16
    unsigned u = __float_as_uint(f);
    return (unsigned short)((u + 0x7FFFu + ((u >> 16) & 1u)) >> 16);
}
__device__ inline float bfh(unsigned short v) {
    return __uint_as_float((unsigned)v << 16);
}
__device__ inline unsigned long long pack_e(int meta, float c) {
    return (unsigned long long)(unsigned)meta |
           ((unsigned long long)(unsigned)__float_as_uint(c) << 32);
}

__global__ __launch_bounds__(256) void k_zero(int* __restrict__ cur1) {
    if (threadIdx.x < NB) cur1[threadIdx.x] = 0;
}

// Blocks [0,NBLK): bin 4096 edges -> LDS counting-sort by bucket -> coalesced
// contiguous run writes into per-bucket reserved chunks.
// Entry u64 = {src:16 | dloc:8 | bucket:8 | coef_f32:32}.
// Blocks [NBLK,..): y16 = bf16(x).
__global__ __launch_bounds__(512) void k_prep(const int* __restrict__ src,
                                              const int* __restrict__ dst,
                                              const float* __restrict__ ew,
                                              const float* __restrict__ pr,
                                              int* __restrict__ cur1,
                                              unsigned long long* __restrict__ stage,
                                              const float4* __restrict__ x4,
                                              ushort4* __restrict__ y16v) {
    int tid = threadIdx.x;
    if (blockIdx.x >= NBLK) {                 // cvt phase
        int i = (blockIdx.x - NBLK) * 512 + tid;
        if (i < NN * DD / 4) {
            float4 v = x4[i];
            y16v[i] = make_ushort4(f2bf(v.x), f2bf(v.y), f2bf(v.z), f2bf(v.w));
        }
        return;
    }
    __shared__ int h[256];
    __shared__ int gb[256];
    __shared__ int sc[256];
    __shared__ unsigned long long sorted[EPB];   // 32 KB
    for (int i = tid; i < 256; i += 512) h[i] = 0;
    __syncthreads();
    int base = blockIdx.x * EPB;
    int n = min(EPB, NE - base);

    unsigned long long ent[8]; int bkt[8]; int lrk[8];
    #pragma unroll
    for (int j = 0; j < 8; j++) {
        int e = base + j * 512 + tid;
        bkt[j] = -1;
        if (e < NE) {
            int d = dst[e];
            int s = src[e];
            float c = ew[e] * pr[s];
            int bk = d >> 8;
            bkt[j] = bk;
            lrk[j] = atomicAdd(&h[bk], 1);
            ent[j] = pack_e(s | ((d & 255) << 16) | (bk << 24), c);
        }
    }
    __syncthreads();
    if (tid < 256) sc[tid] = h[tid];
    __syncthreads();
    #pragma unroll
    for (int o = 1; o < 256; o <<= 1) {
        int t = 0;
        if (tid < 256 && tid >= o) t = sc[tid - o];
        __syncthreads();
        if (tid < 256) sc[tid] += t;             // inclusive scan
        __syncthreads();
    }
    for (int i = tid; i < NB; i += 512)
        gb[i] = h[i] ? atomicAdd(&cur1[i], h[i]) : 0;
    __syncthreads();
    #pragma unroll
    for (int j = 0; j < 8; j++)
        if (bkt[j] >= 0)
            sorted[sc[bkt[j]] - h[bkt[j]] + lrk[j]] = ent[j];
    __syncthreads();
    for (int i = tid; i < n; i += 512) {         // coalesced run writes
        unsigned long long e = sorted[i];
        int bk = ((int)(e >> 24)) & 0xff;
        stage[(size_t)bk * CAPB + gb[bk] + (i - (sc[bk] - h[bk]))] = e;
    }
}

// Per-bucket counting sort by dloc; emits u32 {src | coef_bf16<<16} into the
// first half of the block's own region (all reads precede writes => safe).
__global__ __launch_bounds__(512) void k_sortB(unsigned long long* __restrict__ stage,
                                               const int* __restrict__ cur1,
                                               int* __restrict__ offs,
                                               int* __restrict__ counts) {
    __shared__ int h[256];
    __shared__ int sc[256];
    __shared__ unsigned sorted[CAPB];            // u32, 18.4 KB
    int b = blockIdx.x;
    int tid = threadIdx.x;
    size_t base = (size_t)b * CAPB;
    int n = cur1[b];

    for (int i = tid; i < 256; i += 512) h[i] = 0;
    __syncthreads();

    unsigned e32[9]; int dl[9]; int lrk[9];
    int m = 0;
    for (int i = tid; i < n; i += 512) {
        unsigned long long e = stage[base + i];
        int dloc = ((int)(e >> 16)) & 0xff;
        unsigned cb = (unsigned)(e >> 32);       // coef fp32 bits
        unsigned cbf = (cb + 0x7FFFu + ((cb >> 16) & 1u)) >> 16;  // bf16
        e32[m] = ((unsigned)e & 0xffffu) | (cbf << 16);
        dl[m] = dloc;
        lrk[m] = atomicAdd(&h[dloc], 1);
        m++;
    }
    __syncthreads();
    if (tid < 256) sc[tid] = h[tid];
    __syncthreads();
    #pragma unroll
    for (int o = 1; o < 256; o <<= 1) {
        int t = 0;
        if (tid < 256 && tid >= o) t = sc[tid - o];
        __syncthreads();
        if (tid < 256) sc[tid] += t;             // inclusive
        __syncthreads();
    }
    m = 0;
    for (int i = tid; i < n; i += 512) {
        sorted[sc[dl[m]] - h[dl[m]] + lrk[m]] = e32[m];
        m++;
    }
    __syncthreads();
    unsigned* outp = (unsigned*)(stage + base);  // first half of own region
    for (int i = tid; i < n; i += 512) outp[i] = sorted[i];
    if (tid < 256) {
        int d = (b << 8) + tid;
        if (d < NN) {
            offs[d] = (int)(2 * base) + sc[tid] - h[tid];   // u32 index
            counts[d] = h[tid];
        }
    }
}

// Pull-aggregate: 8 nodes/block, 32 lanes/node, lanes 0..23 own one ushort4
// (4 bf16 channels, 8B gather). Edge loop unrolled x8; u32 entries.
__global__ __launch_bounds__(256) void k_pull(const ushort4* __restrict__ y16v,
                                              const float4* __restrict__ x4,
                                              const int* __restrict__ offs,
                                              const int* __restrict__ counts,
                                              const unsigned* __restrict__ ep,
                                              float4* __restrict__ out4) {
    int g = blockIdx.x * 8 + (threadIdx.x >> 5);
    int lane = threadIdx.x & 31;
    if (g >= NN || lane >= 24) return;
    int beg = offs[g];
    int deg = counts[g];
    float ax = 0.f, ay = 0.f, az = 0.f, aw = 0.f;
    int k = 0;
    for (; k + 8 <= deg; k += 8) {
        unsigned e[8];
        #pragma unroll
        for (int j = 0; j < 8; j++) e[j] = ep[beg + k + j];
        ushort4 u[8];
        #pragma unroll
        for (int j = 0; j < 8; j++)
            u[j] = y16v[(size_t)(e[j] & 0xffff) * 24 + lane];
        #pragma unroll
        for (int j = 0; j < 8; j++) {
            float c = bfh((unsigned short)(e[j] >> 16));
            ax += c * bfh(u[j].x);
            ay += c * bfh(u[j].y);
            az += c * bfh(u[j].z);
            aw += c * bfh(u[j].w);
        }
    }
    for (; k + 4 <= deg; k += 4) {
        unsigned e[4];
        #pragma unroll
        for (int j = 0; j < 4; j++) e[j] = ep[beg + k + j];
        ushort4 u[4];
        #pragma unroll
        for (int j = 0; j < 4; j++)
            u[j] = y16v[(size_t)(e[j] & 0xffff) * 24 + lane];
        #pragma unroll
        for (int j = 0; j < 4; j++) {
            float c = bfh((unsigned short)(e[j] >> 16));
            ax += c * bfh(u[j].x);
            ay += c * bfh(u[j].y);
            az += c * bfh(u[j].z);
            aw += c * bfh(u[j].w);
        }
    }
    for (; k < deg; k++) {
        unsigned e = ep[beg + k];
        ushort4 u = y16v[(size_t)(e & 0xffff) * 24 + lane];
        float c = bfh((unsigned short)(e >> 16));
        ax += c * bfh(u.x);
        ay += c * bfh(u.y);
        az += c * bfh(u.z);
        aw += c * bfh(u.w);
    }
    float4 xn = x4[(size_t)g * 24 + lane];
    out4[(size_t)g * 24 + lane] = make_float4(ax + xn.x, ay + xn.y,
                                              az + xn.z, aw + xn.w);
}

// In-place row GEMM (unchanged, proven): io[r,o]=sum_d io[r,d]*Wt[d,o]+b[o].
constexpr int SWS = 100;
__global__ __launch_bounds__(256, 4) void k_gemm(float* __restrict__ io,
                                                 const float* __restrict__ W,
                                                 const float* __restrict__ b) {
    __shared__ float sWt[DD * SWS];   // [d][o]
    int tid = threadIdx.x;
    for (int i = tid; i < DD * DD; i += 256) {
        int o = i / DD, d = i - o * DD;
        sWt[d * SWS + o] = W[i];
    }
    __syncthreads();

    int wave = tid >> 6, lane = tid & 63;
    int og = lane & 7, rgl = lane >> 3;
    int o0 = og * 12;
    int rbase = blockIdx.x * 128 + wave * 32 + rgl;
    const float4* io4 = (const float4*)io;

    int r[4];
    #pragma unroll
    for (int t = 0; t < 4; t++) {
        int rr = rbase + 8 * t;
        r[t] = (rr < NN) ? rr : (NN - 1);
    }

    float acc[4][12];
    #pragma unroll
    for (int t = 0; t < 4; t++)
        #pragma unroll
        for (int m = 0; m < 12; m++) acc[t][m] = 0.f;

    for (int d4 = 0; d4 < 24; d4++) {
        float4 xv[4];
        #pragma unroll
        for (int t = 0; t < 4; t++) xv[t] = io4[(size_t)r[t] * 24 + d4];
        #pragma unroll
        for (int dj = 0; dj < 4; dj++) {
            const float* wp = &sWt[(d4 * 4 + dj) * SWS + o0];
            float4 w0 = *(const float4*)(wp);
            float4 w1 = *(const float4*)(wp + 4);
            float4 w2 = *(const float4*)(wp + 8);
            #pragma unroll
            for (int t = 0; t < 4; t++) {
                float xs = (dj == 0) ? xv[t].x : (dj == 1) ? xv[t].y
                         : (dj == 2) ? xv[t].z : xv[t].w;
                acc[t][0]  += xs * w0.x;  acc[t][1]  += xs * w0.y;
                acc[t][2]  += xs * w0.z;  acc[t][3]  += xs * w0.w;
                acc[t][4]  += xs * w1.x;  acc[t][5]  += xs * w1.y;
                acc[t][6]  += xs * w1.z;  acc[t][7]  += xs * w1.w;
                acc[t][8]  += xs * w2.x;  acc[t][9]  += xs * w2.y;
                acc[t][10] += xs * w2.z;  acc[t][11] += xs * w2.w;
            }
        }
    }

    float4 b0 = *(const float4*)(b + o0);
    float4 b1 = *(const float4*)(b + o0 + 4);
    float4 b2 = *(const float4*)(b + o0 + 8);
    float4* io4w = (float4*)io;
    #pragma unroll
    for (int t = 0; t < 4; t++) {
        int rr = rbase + 8 * t;
        if (rr < NN) {
            size_t base = (size_t)rr * 24 + og * 3;
            io4w[base + 0] = make_float4(acc[t][0] + b0.x, acc[t][1] + b0.y,
                                         acc[t][2] + b0.z, acc[t][3] + b0.w);
            io4w[base + 1] = make_float4(acc[t][4] + b1.x, acc[t][5] + b1.y,
                                         acc[t][6] + b1.z, acc[t][7] + b1.w);
            io4w[base + 2] = make_float4(acc[t][8] + b2.x, acc[t][9] + b2.y,
                                         acc[t][10] + b2.z, acc[t][11] + b2.w);
        }
    }
}

extern "C" void kernel_launch(void* const* d_in, const int* in_sizes, int n_in,
                              void* d_out, int out_size, void* d_ws, size_t ws_size,
                              hipStream_t stream) {
    const float* x  = (const float*)d_in[0];
    const int*   ei = (const int*)d_in[1];   // [2,E]: [0..E)=src, [E..2E)=dst
    const float* ew = (const float*)d_in[2];
    const float* pr = (const float*)d_in[3];
    const float* W  = (const float*)d_in[4];
    const float* b  = (const float*)d_in[5];
    float* out = (float*)d_out;

    // ws layout (~17.3 MB)
    unsigned long long* stage = (unsigned long long*)d_ws;       // NB*CAPB u64
    unsigned short* y16 = (unsigned short*)(stage + (size_t)NB * CAPB);  // 9.6MB
    int* cur1   = (int*)(y16 + (size_t)NN * DD);      // 196
    int* offs   = cur1 + NB;                          // 50000
    int* counts = offs + NN;                          // 50000

    const int* src = ei;
    const int* dst = ei + NE;

    k_zero<<<1, 256, 0, stream>>>(cur1);
    k_prep<<<NBLK + NCVT, 512, 0, stream>>>(src, dst, ew, pr, cur1, stage,
                                            (const float4*)x, (ushort4*)y16);
    k_sortB<<<NB, 512, 0, stream>>>(stage, cur1, offs, counts);
    k_pull<<<(NN + 7) / 8, 256, 0, stream>>>((const ushort4*)y16, (const float4*)x,
                                             offs, counts, (const unsigned*)stage,
                                             (float4*)out);
    k_gemm<<<(NN + 127) / 128, 256, 0, stream>>>(out, W, b);
}

// Round 11
// 141.548 us; speedup vs baseline: 1.3733x; 1.0667x over previous
//
#include <hip/hip_runtime.h>

// CGCConv: out = (scatter_add(ew*pr[src]*x[src], dst) + x) @ W.T + b
// N=50000, E=800000, D=96, fp32.
//
// Round 11 = Round 10 (151.0us best) + MFMA epilogue GEMM:
//  - k_pull writes io16 = bf16(aggr+x) (9.6MB) instead of fp32 d_out.
//  - k_gemm: mfma_f32_16x16x32_bf16. Per wave: 16 rows x 96 cols.
//    A-frag straight from global (A[m=lane&15][k=quad*8+j], HW-verified),
//    W pre-swizzled to LDS as ds_read_b128-ready B-frags (B[k][n], n=lane&15,
//    k=quad*8+j), C/D per verified col=lane&15,row=quad*4+reg.
//  - prep/sortB/pull gather path unchanged from R10.
// Pipeline (5 launches): zero -> prep -> sortB -> pull -> gemm.

constexpr int NN = 50000;
constexpr int NE = 800000;
constexpr int DD = 96;
constexpr int NB = 196;                       // buckets: dst>>8 (256 nodes)
constexpr int CAPB = 4608;                    // mu=4082 + 8 sigma
constexpr int EPB = 4096;                     // edges per binA block
constexpr int NBLK = (NE + EPB - 1) / EPB;    // 196
constexpr int NCVT = (NN * DD / 4 + 511) / 512;  // 2344 cvt blocks

using s8v = __attribute__((ext_vector_type(8))) short;   // 8 bf16
using f4v = __attribute__((ext_vector_type(4))) float;   // 4 fp32

__device__ inline unsigned short f2bf(float f) {    // RNE fp32->bf16
    unsigned u = __float_as_uint(f);
    return (unsigned short)((u + 0x7FFFu + ((u >> 16) & 1u)) >> 16);
}
__device__ inline float bfh(unsigned short v) {
    return __uint_as_float((unsigned)v << 16);
}
__device__ inline unsigned long long pack_e(int meta, float c) {
    return (unsigned long long)(unsigned)meta |
           ((unsigned long long)(unsigned)__float_as_uint(c) << 32);
}

__global__ __launch_bounds__(256) void k_zero(int* __restrict__ cur1) {
    if (threadIdx.x < NB) cur1[threadIdx.x] = 0;
}

// Blocks [0,NBLK): bin 4096 edges -> LDS counting-sort by bucket -> coalesced
// run writes. Entry u64 = {src:16 | dloc:8 | bucket:8 | coef_f32:32}.
// Blocks [NBLK,..): y16 = bf16(x).
__global__ __launch_bounds__(512) void k_prep(const int* __restrict__ src,
                                              const int* __restrict__ dst,
                                              const float* __restrict__ ew,
                                              const float* __restrict__ pr,
                                              int* __restrict__ cur1,
                                              unsigned long long* __restrict__ stage,
                                              const float4* __restrict__ x4,
                                              ushort4* __restrict__ y16v) {
    int tid = threadIdx.x;
    if (blockIdx.x >= NBLK) {                 // cvt phase
        int i = (blockIdx.x - NBLK) * 512 + tid;
        if (i < NN * DD / 4) {
            float4 v = x4[i];
            y16v[i] = make_ushort4(f2bf(v.x), f2bf(v.y), f2bf(v.z), f2bf(v.w));
        }
        return;
    }
    __shared__ int h[256];
    __shared__ int gb[256];
    __shared__ int sc[256];
    __shared__ unsigned long long sorted[EPB];   // 32 KB
    for (int i = tid; i < 256; i += 512) h[i] = 0;
    __syncthreads();
    int base = blockIdx.x * EPB;
    int n = min(EPB, NE - base);

    unsigned long long ent[8]; int bkt[8]; int lrk[8];
    #pragma unroll
    for (int j = 0; j < 8; j++) {
        int e = base + j * 512 + tid;
        bkt[j] = -1;
        if (e < NE) {
            int d = dst[e];
            int s = src[e];
            float c = ew[e] * pr[s];
            int bk = d >> 8;
            bkt[j] = bk;
            lrk[j] = atomicAdd(&h[bk], 1);
            ent[j] = pack_e(s | ((d & 255) << 16) | (bk << 24), c);
        }
    }
    __syncthreads();
    if (tid < 256) sc[tid] = h[tid];
    __syncthreads();
    #pragma unroll
    for (int o = 1; o < 256; o <<= 1) {
        int t = 0;
        if (tid < 256 && tid >= o) t = sc[tid - o];
        __syncthreads();
        if (tid < 256) sc[tid] += t;             // inclusive scan
        __syncthreads();
    }
    for (int i = tid; i < NB; i += 512)
        gb[i] = h[i] ? atomicAdd(&cur1[i], h[i]) : 0;
    __syncthreads();
    #pragma unroll
    for (int j = 0; j < 8; j++)
        if (bkt[j] >= 0)
            sorted[sc[bkt[j]] - h[bkt[j]] + lrk[j]] = ent[j];
    __syncthreads();
    for (int i = tid; i < n; i += 512) {         // coalesced run writes
        unsigned long long e = sorted[i];
        int bk = ((int)(e >> 24)) & 0xff;
        stage[(size_t)bk * CAPB + gb[bk] + (i - (sc[bk] - h[bk]))] = e;
    }
}

// Per-bucket counting sort by dloc; emits u32 {src | coef_bf16<<16} into the
// first half of the block's own region (all reads precede writes => safe).
__global__ __launch_bounds__(512) void k_sortB(unsigned long long* __restrict__ stage,
                                               const int* __restrict__ cur1,
                                               int* __restrict__ offs,
                                               int* __restrict__ counts) {
    __shared__ int h[256];
    __shared__ int sc[256];
    __shared__ unsigned sorted[CAPB];            // u32, 18.4 KB
    int b = blockIdx.x;
    int tid = threadIdx.x;
    size_t base = (size_t)b * CAPB;
    int n = cur1[b];

    for (int i = tid; i < 256; i += 512) h[i] = 0;
    __syncthreads();

    unsigned e32[9]; int dl[9]; int lrk[9];
    int m = 0;
    for (int i = tid; i < n; i += 512) {
        unsigned long long e = stage[base + i];
        int dloc = ((int)(e >> 16)) & 0xff;
        unsigned cb = (unsigned)(e >> 32);       // coef fp32 bits
        unsigned cbf = (cb + 0x7FFFu + ((cb >> 16) & 1u)) >> 16;  // bf16
        e32[m] = ((unsigned)e & 0xffffu) | (cbf << 16);
        dl[m] = dloc;
        lrk[m] = atomicAdd(&h[dloc], 1);
        m++;
    }
    __syncthreads();
    if (tid < 256) sc[tid] = h[tid];
    __syncthreads();
    #pragma unroll
    for (int o = 1; o < 256; o <<= 1) {
        int t = 0;
        if (tid < 256 && tid >= o) t = sc[tid - o];
        __syncthreads();
        if (tid < 256) sc[tid] += t;             // inclusive
        __syncthreads();
    }
    m = 0;
    for (int i = tid; i < n; i += 512) {
        sorted[sc[dl[m]] - h[dl[m]] + lrk[m]] = e32[m];
        m++;
    }
    __syncthreads();
    unsigned* outp = (unsigned*)(stage + base);  // first half of own region
    for (int i = tid; i < n; i += 512) outp[i] = sorted[i];
    if (tid < 256) {
        int d = (b << 8) + tid;
        if (d < NN) {
            offs[d] = (int)(2 * base) + sc[tid] - h[tid];   // u32 index
            counts[d] = h[tid];
        }
    }
}

// Pull-aggregate: 8 nodes/block, 32 lanes/node, lanes 0..23 own one ushort4
// (4 bf16 channels, 8B gather). Writes io16 = bf16(aggr + x).
__global__ __launch_bounds__(256) void k_pull(const ushort4* __restrict__ y16v,
                                              const float4* __restrict__ x4,
                                              const int* __restrict__ offs,
                                              const int* __restrict__ counts,
                                              const unsigned* __restrict__ ep,
                                              ushort4* __restrict__ io16v) {
    int g = blockIdx.x * 8 + (threadIdx.x >> 5);
    int lane = threadIdx.x & 31;
    if (g >= NN || lane >= 24) return;
    int beg = offs[g];
    int deg = counts[g];
    float ax = 0.f, ay = 0.f, az = 0.f, aw = 0.f;
    int k = 0;
    for (; k + 8 <= deg; k += 8) {
        unsigned e[8];
        #pragma unroll
        for (int j = 0; j < 8; j++) e[j] = ep[beg + k + j];
        ushort4 u[8];
        #pragma unroll
        for (int j = 0; j < 8; j++)
            u[j] = y16v[(size_t)(e[j] & 0xffff) * 24 + lane];
        #pragma unroll
        for (int j = 0; j < 8; j++) {
            float c = bfh((unsigned short)(e[j] >> 16));
            ax += c * bfh(u[j].x);
            ay += c * bfh(u[j].y);
            az += c * bfh(u[j].z);
            aw += c * bfh(u[j].w);
        }
    }
    for (; k + 4 <= deg; k += 4) {
        unsigned e[4];
        #pragma unroll
        for (int j = 0; j < 4; j++) e[j] = ep[beg + k + j];
        ushort4 u[4];
        #pragma unroll
        for (int j = 0; j < 4; j++)
            u[j] = y16v[(size_t)(e[j] & 0xffff) * 24 + lane];
        #pragma unroll
        for (int j = 0; j < 4; j++) {
            float c = bfh((unsigned short)(e[j] >> 16));
            ax += c * bfh(u[j].x);
            ay += c * bfh(u[j].y);
            az += c * bfh(u[j].z);
            aw += c * bfh(u[j].w);
        }
    }
    for (; k < deg; k++) {
        unsigned e = ep[beg + k];
        ushort4 u = y16v[(size_t)(e & 0xffff) * 24 + lane];
        float c = bfh((unsigned short)(e >> 16));
        ax += c * bfh(u.x);
        ay += c * bfh(u.y);
        az += c * bfh(u.z);
        aw += c * bfh(u.w);
    }
    float4 xn = x4[(size_t)g * 24 + lane];
    io16v[(size_t)g * 24 + lane] = make_ushort4(f2bf(ax + xn.x), f2bf(ay + xn.y),
                                                f2bf(az + xn.z), f2bf(aw + xn.w));
}

// MFMA GEMM: out[r,o] = sum_d io16[r,d]*W[o,d] + b[o], fp32 out.
// Wave = 16-row x 96-col strip. A from global (m=lane&15, k=quad*8+j).
// B-frags pre-swizzled in LDS: frag f=(ks*6+nt), lane holds B[k][n] with
// n = nt*16 + (lane&15), k = ks*32 + quad*8 + j. C/D: col=lane&15,
// row = quad*4 + reg (HW-verified mappings).
__global__ __launch_bounds__(256) void k_gemm(const unsigned short* __restrict__ io16,
                                              const float* __restrict__ W,
                                              const float* __restrict__ b,
                                              float* __restrict__ out) {
    __shared__ short bfr[18 * 64 * 8];     // 18 frags x 64 lanes x 8 bf16 = 18.4KB
    int tid = threadIdx.x;
    for (int i = tid; i < 18 * 512; i += 256) {
        int f = i >> 9, r = i & 511;
        int lane = r >> 3, j = r & 7;
        int ks = f / 6, nt = f - 6 * ks;
        int n = nt * 16 + (lane & 15);
        int k = ks * 32 + (lane >> 4) * 8 + j;
        bfr[i] = (short)f2bf(W[n * DD + k]);
    }
    __syncthreads();

    int wave = tid >> 6, lane = tid & 63;
    int quad = lane >> 4, m16 = lane & 15;
    int r0 = blockIdx.x * 64 + wave * 16;
    int rowa = r0 + m16;
    if (rowa >= NN) rowa = NN - 1;           // clamped A read, store masked

    f4v acc[6];
    #pragma unroll
    for (int nt = 0; nt < 6; nt++) acc[nt] = (f4v){0.f, 0.f, 0.f, 0.f};

    #pragma unroll
    for (int ks = 0; ks < 3; ks++) {
        s8v a = *(const s8v*)(io16 + (size_t)rowa * DD + ks * 32 + quad * 8);
        #pragma unroll
        for (int nt = 0; nt < 6; nt++) {
            s8v bb = *(const s8v*)&bfr[((ks * 6 + nt) * 64 + lane) * 8];
            acc[nt] = __builtin_amdgcn_mfma_f32_16x16x32_bf16(a, bb, acc[nt], 0, 0, 0);
        }
    }

    #pragma unroll
    for (int nt = 0; nt < 6; nt++) {
        float bias = b[nt * 16 + m16];
        #pragma unroll
        for (int reg = 0; reg < 4; reg++) {
            int rr = r0 + quad * 4 + reg;
            if (rr < NN)
                out[(size_t)rr * DD + nt * 16 + m16] = acc[nt][reg] + bias;
        }
    }
}

extern "C" void kernel_launch(void* const* d_in, const int* in_sizes, int n_in,
                              void* d_out, int out_size, void* d_ws, size_t ws_size,
                              hipStream_t stream) {
    const float* x  = (const float*)d_in[0];
    const int*   ei = (const int*)d_in[1];   // [2,E]: [0..E)=src, [E..2E)=dst
    const float* ew = (const float*)d_in[2];
    const float* pr = (const float*)d_in[3];
    const float* W  = (const float*)d_in[4];
    const float* b  = (const float*)d_in[5];
    float* out = (float*)d_out;

    // ws layout (~26.8 MB)
    unsigned long long* stage = (unsigned long long*)d_ws;       // NB*CAPB u64
    unsigned short* y16 = (unsigned short*)(stage + (size_t)NB * CAPB);  // 9.6MB
    int* cur1   = (int*)(y16 + (size_t)NN * DD);      // 196
    int* offs   = cur1 + NB;                          // 50000
    int* counts = offs + NN;                          // 50000
    unsigned short* io16 = (unsigned short*)(counts + NN);       // 9.6MB

    const int* src = ei;
    const int* dst = ei + NE;

    k_zero<<<1, 256, 0, stream>>>(cur1);
    k_prep<<<NBLK + NCVT, 512, 0, stream>>>(src, dst, ew, pr, cur1, stage,
                                            (const float4*)x, (ushort4*)y16);
    k_sortB<<<NB, 512, 0, stream>>>(stage, cur1, offs, counts);
    k_pull<<<(NN + 7) / 8, 256, 0, stream>>>((const ushort4*)y16, (const float4*)x,
                                             offs, counts, (const unsigned*)stage,
                                             (ushort4*)io16);
    k_gemm<<<(NN + 63) / 64, 256, 0, stream>>>(io16, W, b, out);
}